// Round 3
// baseline (243.994 us; speedup 1.0000x reference)
//
#include <hip/hip_runtime.h>
#include <stdint.h>

typedef unsigned short u16;
typedef unsigned int   u32;
typedef __bf16 bf16x8_t __attribute__((ext_vector_type(8)));
typedef float  f32x4_t  __attribute__((ext_vector_type(4)));

#define MFMA16(a, b, c) __builtin_amdgcn_mfma_f32_16x16x32_bf16((a), (b), (c), 0, 0, 0)

__device__ __forceinline__ float bf2f(u16 u) {
    union { u32 i; float f; } c; c.i = ((u32)u) << 16; return c.f;
}
__device__ __forceinline__ u16 f2bf(float f) {
    union { float f; u32 i; } c; c.f = f;
    u32 x = c.i;
    return (u16)((x + 0x7fffu + ((x >> 16) & 1u)) >> 16);  // RNE
}

// Direct global->LDS DMA, 16B per lane. LDS dest must be wave-uniform base
// (HW adds lane*16); global src is per-lane (carries the XOR swizzle).
// C-style casts -> clang addrspacecast (generic->AS1 / generic->AS3).
typedef const unsigned int __attribute__((address_space(1)))* gas_t;
typedef unsigned int __attribute__((address_space(3)))* las_t;
__device__ __forceinline__ void gload16(const u16* g, const u16* l) {
    __builtin_amdgcn_global_load_lds((gas_t)(const void*)g, (las_t)(void*)l, 16, 0, 0);
}

// ---------------------------------------------------------------------------
// Block-local input-dtype detection (flag=1 -> fp32 inputs). Even u16 halves
// of fp32 data have ~32% "sane" bf16 exponents; real bf16 data ~100%.
// Deterministic, same work every call; 256-thread blocks only.
// ---------------------------------------------------------------------------
__device__ __forceinline__ u32 detect_fp32(const u16* __restrict__ xu,
                                           int tid, int* wcnt) {
    u16 w = xu[2 * tid];
    int e = (w >> 7) & 0xff;
    int ok = (e >= 80 && e <= 160) ? 1 : 0;
    unsigned long long m = __ballot(ok);
    if ((tid & 63) == 0) wcnt[tid >> 6] = __popcll(m);
    __syncthreads();
    int cnt = wcnt[0] + wcnt[1] + wcnt[2] + wcnt[3];
    return (cnt < 160) ? 1u : 0u;
}

// ---------------------------------------------------------------------------
// Kernel W: convert W1/b1/W2/b2 to bf16 copies in workspace.
// ---------------------------------------------------------------------------
__global__ __launch_bounds__(256) void conv_w(const u16* __restrict__ xu,
                                              const void* __restrict__ W1,
                                              const void* __restrict__ b1,
                                              const void* __restrict__ W2,
                                              const void* __restrict__ b2,
                                              u16* __restrict__ W1b,
                                              u16* __restrict__ b1b,
                                              u16* __restrict__ W2b,
                                              u16* __restrict__ b2b) {
    __shared__ int wcnt[4];
    u32 f = detect_fp32(xu, threadIdx.x, wcnt);
    int i = blockIdx.x * 256 + threadIdx.x;
    const int n1 = 196608, n2 = 768, n3 = 65536;
    const void* src; u16* dst; int li;
    if (i < n1)                { src = W1; dst = W1b; li = i; }
    else if (i < n1 + n2)      { src = b1; dst = b1b; li = i - n1; }
    else if (i < n1 + n2 + n3) { src = W2; dst = W2b; li = i - n1 - n2; }
    else                       { src = b2; dst = b2b; li = i - n1 - n2 - n3; }
    u16 v;
    if (f) v = f2bf(((const float*)src)[li]);
    else   v = ((const u16*)src)[li];
    dst[li] = v;
}

// ---------------------------------------------------------------------------
// Kernel X: x [b][c][hw] -> xT [b*4096+hw][c] bf16 (pixel-major)
// ---------------------------------------------------------------------------
__global__ __launch_bounds__(256) void conv_x(const void* __restrict__ X,
                                              u16* __restrict__ XT) {
    __shared__ __align__(16) u16 tile[64][68];
    __shared__ int wcnt[4];
    const int tid = threadIdx.x;
    u32 f = detect_fp32((const u16*)X, tid, wcnt);
    const int b = blockIdx.z, c0 = blockIdx.y * 64, h0 = blockIdx.x * 64;
    const int col = tid & 63, rq = tid >> 6;
    if (f) {
        const float* Xf = (const float*)X;
#pragma unroll
        for (int i = 0; i < 16; i++) {
            int row = i * 4 + rq;
            tile[row][col] = f2bf(Xf[((size_t)(b * 256 + c0 + row)) * 4096 + h0 + col]);
        }
    } else {
        const u16* Xh = (const u16*)X;
#pragma unroll
        for (int i = 0; i < 16; i++) {
            int row = i * 4 + rq;
            tile[row][col] = Xh[((size_t)(b * 256 + c0 + row)) * 4096 + h0 + col];
        }
    }
    __syncthreads();
#pragma unroll
    for (int i = 0; i < 16; i++) {
        int row = i * 4 + rq;
        XT[((size_t)(b * 4096 + h0 + row)) * 256 + c0 + col] = tile[col][row];
    }
}

// ---------------------------------------------------------------------------
// Kernel 1: qkv = xT @ W1^T + b1 with 96-wide n-tiles (= one head exactly).
// Staging via global_load_lds (linear LDS dest + pre-swizzled global source:
// chunk = (lane&7)^(lane>>3), an involution of the read-side XOR).
// Block swizzle: the 8 head-blocks sharing an A-tile are 8 ids apart -> same
// XCD (id%8 heuristic) and temporally adjacent -> A-tile re-reads hit L2.
// Epilogue: LDS roundtrip -> pixel-major per-head Q2/K2/V2 [b][head][hw][e].
// ---------------------------------------------------------------------------
__global__ __launch_bounds__(256) void gemm_qkv(const u16* __restrict__ XT,
                                                const u16* __restrict__ W1,
                                                const u16* __restrict__ b1,
                                                u16* __restrict__ Q2,
                                                u16* __restrict__ K2,
                                                u16* __restrict__ V2) {
    __shared__ __align__(16) u16 smem[128 * 64 + 96 * 64];  // 28 KB
    u16* sA = smem;
    u16* sB = smem + 128 * 64;
    u16* Cs = smem;  // reused after barrier: 128 x 104 = 13312 <= 14336

    const int tid  = threadIdx.x;
    const int lane = tid & 63, wave = tid >> 6;
    const int quad = lane >> 4, l16 = lane & 15;
    const int wm = wave * 32;
    const int bx = blockIdx.x;
    const int bm = (bx >> 6) * 8 + (bx & 7);  // 512 m-tiles
    const int h  = (bx >> 3) & 7;             // 8 heads
    const int o_base = h * 96;

    f32x4_t acc[2][6];
    const f32x4_t zz = {0.f, 0.f, 0.f, 0.f};
#pragma unroll
    for (int i = 0; i < 2; i++)
#pragma unroll
        for (int j = 0; j < 6; j++) acc[i][j] = zz;

    // per-lane pre-swizzled staging addresses (k-invariant, hoisted)
    const int sub = lane >> 3;              // row-within-8
    const int cpw = (lane & 7) ^ sub;       // global chunk for this lane
    const u16* gA[4]; const u16* gB[3];
    const u16* lA[4]; const u16* lB[3];
#pragma unroll
    for (int i = 0; i < 4; i++) {
        int r8 = (wave * 4 + i) * 8;
        gA[i] = XT + ((size_t)(bm * 128 + r8 + sub)) * 256 + cpw * 8;
        lA[i] = sA + r8 * 64;               // wave-uniform LDS base
    }
#pragma unroll
    for (int i = 0; i < 3; i++) {
        int r8 = (wave * 3 + i) * 8;
        gB[i] = W1 + ((size_t)(o_base + r8 + sub)) * 256 + cpw * 8;
        lB[i] = sB + r8 * 64;
    }

    for (int kt = 0; kt < 256; kt += 64) {
        __syncthreads();
#pragma unroll
        for (int i = 0; i < 4; i++) gload16(gA[i] + kt, lA[i]);
#pragma unroll
        for (int i = 0; i < 3; i++) gload16(gB[i] + kt, lB[i]);
        __syncthreads();  // implicit vmcnt(0) drains the DMA
#pragma unroll
        for (int ks = 0; ks < 2; ks++) {
            bf16x8_t af[2], bg[6];
#pragma unroll
            for (int i = 0; i < 2; i++) {
                int row = wm + i * 16 + l16;
                int cp = (ks * 4 + quad) ^ (row & 7);
                af[i] = *(const bf16x8_t*)(sA + row * 64 + cp * 8);
            }
#pragma unroll
            for (int j = 0; j < 6; j++) {
                int row = j * 16 + l16;
                int cp = (ks * 4 + quad) ^ (row & 7);
                bg[j] = *(const bf16x8_t*)(sB + row * 64 + cp * 8);
            }
#pragma unroll
            for (int i = 0; i < 2; i++)
#pragma unroll
                for (int j = 0; j < 6; j++)
                    acc[i][j] = MFMA16(af[i], bg[j], acc[i][j]);
        }
    }

    // ---- epilogue: bias + bf16 -> Cs[128 m][col 96] (stride 104) ----
    __syncthreads();
#pragma unroll
    for (int j = 0; j < 6; j++) {
        float bias = bf2f(b1[o_base + j * 16 + l16]);
#pragma unroll
        for (int i = 0; i < 2; i++) {
            int m = wm + i * 16 + quad * 4;
#pragma unroll
            for (int r = 0; r < 4; r++)
                Cs[(m + r) * 104 + j * 16 + l16] = f2bf(acc[i][j][r] + bias);
        }
    }
    __syncthreads();

    // ---- repack: col = 3*e + w -> tensor w, pixel-major [b][h][hw][e] ----
    const int b = bm >> 5;
    const int hw0 = (bm & 31) * 128;
    const size_t hb = ((size_t)(b * 8 + h)) * 4096;
#pragma unroll
    for (int it = 0; it < 2; it++) {
        int u = it * 256 + tid;
        int px = u >> 2, ch = u & 3;
        size_t gaddr = (hb + hw0 + px) * 32 + ch * 8;
#pragma unroll
        for (int w = 0; w < 3; w++) {
            u16 vals[8];
#pragma unroll
            for (int jj = 0; jj < 8; jj++)
                vals[jj] = Cs[px * 104 + 3 * (ch * 8 + jj) + w];
            uint4 pk;
            pk.x = (u32)vals[0] | ((u32)vals[1] << 16);
            pk.y = (u32)vals[2] | ((u32)vals[3] << 16);
            pk.z = (u32)vals[4] | ((u32)vals[5] << 16);
            pk.w = (u32)vals[6] | ((u32)vals[7] << 16);
            u16* dst = (w == 0) ? Q2 : (w == 1) ? K2 : V2;
            *(uint4*)(dst + gaddr) = pk;
        }
    }
}

// ---------------------------------------------------------------------------
// Kernel 2: windowed overlapping attention (Q 8x8, K/V 12x12 zero-padded).
// Q loaded straight to registers (per-lane 16B = the exact MFMA A-fragment).
// LDS plan (32256 B -> 5 blocks/CU, was 37376 -> 4):
//   Ks   [144][40] ... overlaid by Ps [64][168] after QK^T   21504 B
//   Vt   [32][168] XOR-swizzled cols (conflict-free transpose) 10752 B
// Vt swizzle: phys_col = log_col ^ ((e>>3)<<3) — bijection on [0,160),
// keeps 8-blocks contiguous (b128-safe), distributes the 4 writer lanes
// (e0 = 0,8,16,24 at same px) onto 4 distinct banks.
// ---------------------------------------------------------------------------
__global__ __launch_bounds__(256) void attn_kernel(const u16* __restrict__ Q2,
                                                   const u16* __restrict__ K2,
                                                   const u16* __restrict__ V2,
                                                   u16* __restrict__ Op) {
    __shared__ __align__(16) u16 smem[16128];  // 32256 B
    u16* Ks = smem;               // [k][e]    stride 40   (dead after QK^T)
    u16* Ps = smem;               // [q][k]    stride 168  (overlay)
    u16* Vt = smem + 10752;       // [e][k]    stride 168, swizzled cols

    const int tid  = threadIdx.x;
    const int lane = tid & 63, wave = tid >> 6;
    const int quad = lane >> 4, l16 = lane & 15;
    const int win = blockIdx.x, head = blockIdx.y, b = blockIdx.z;
    const int wi = win >> 3, wj = win & 7;
    const size_t hb = ((size_t)(b * 8 + head)) * 4096;

    // ---- Q straight to register: row wave*16+l16, chunk quad (16B) ----
    bf16x8_t aF;
    {
        int px = wave * 16 + l16;
        int qy = px >> 3, qx = px & 7;
        aF = *(const bf16x8_t*)(Q2 + (hb + (wi * 8 + qy) * 64 + wj * 8 + qx) * 32 + quad * 8);
    }
    // ---- stage K + V (merged, one addr calc); V transposed w/ swizzle ----
    for (int u = tid; u < 576; u += 256) {
        int px = u >> 2, ch = u & 3;
        int py = px / 12, kx = px - py * 12;
        int gy = wi * 8 - 2 + py, gx = wj * 8 - 2 + kx;
        uint4 kv = make_uint4(0, 0, 0, 0), vv = make_uint4(0, 0, 0, 0);
        if (gy >= 0 && gy < 64 && gx >= 0 && gx < 64) {
            size_t off = (hb + gy * 64 + gx) * 32 + ch * 8;
            kv = *(const uint4*)(K2 + off);
            vv = *(const uint4*)(V2 + off);
        }
        *(uint4*)(Ks + px * 40 + ch * 8) = kv;
        int colp = px ^ (ch << 3);
        int e0 = ch * 8;
        u32 w0[4] = {vv.x, vv.y, vv.z, vv.w};
#pragma unroll
        for (int p = 0; p < 4; p++) {
            Vt[(e0 + 2 * p    ) * 168 + colp] = (u16)(w0[p] & 0xffff);
            Vt[(e0 + 2 * p + 1) * 168 + colp] = (u16)(w0[p] >> 16);
        }
    }
    // ---- Vt pad cols 144..159 (swizzled addresses) ----
    for (int t = tid; t < 512; t += 256) {
        int e = t >> 4, cl = 144 + (t & 15);
        Vt[e * 168 + (cl ^ ((e >> 3) << 3))] = 0;
    }
    __syncthreads();

    // ---- scores: S_raw = Q K^T (wave w owns q rows 16w..16w+15) ----
    float s[9][4];
    {
        const f32x4_t zz = {0.f, 0.f, 0.f, 0.f};
#pragma unroll
        for (int j = 0; j < 9; j++) {
            bf16x8_t bF = *(const bf16x8_t*)(Ks + (j * 16 + l16) * 40 + quad * 8);
            f32x4_t d = MFMA16(aF, bF, zz);
#pragma unroll
            for (int r = 0; r < 4; r++) s[j][r] = d[r];
        }
    }
    // ---- row max on raw scores (scale folded into exp arg) ----
    float mx[4] = {-1e30f, -1e30f, -1e30f, -1e30f};
#pragma unroll
    for (int j = 0; j < 9; j++)
#pragma unroll
        for (int r = 0; r < 4; r++) mx[r] = fmaxf(mx[r], s[j][r]);
#pragma unroll
    for (int off = 1; off < 16; off <<= 1)
#pragma unroll
        for (int r = 0; r < 4; r++) mx[r] = fmaxf(mx[r], __shfl_xor(mx[r], off, 16));

    __syncthreads();  // Ks fully consumed by all waves; Ps overlay begins

    // ---- Ps pad cols 144..159 for this wave's 16 rows (one b64/lane) ----
    *(unsigned long long*)(Ps + (wave * 16 + l16) * 168 + 144 + quad * 4) = 0ULL;

    const float scale = 0.17677669529663687f;  // 1/sqrt(32)
    float msc[4];
#pragma unroll
    for (int r = 0; r < 4; r++) msc[r] = mx[r] * scale;
    float sm[4] = {0.f, 0.f, 0.f, 0.f};
#pragma unroll
    for (int j = 0; j < 9; j++) {
#pragma unroll
        for (int r = 0; r < 4; r++) {
            float p = __expf(fmaf(s[j][r], scale, -msc[r]));
            sm[r] += p;
            Ps[(wave * 16 + quad * 4 + r) * 168 + j * 16 + l16] = f2bf(p);
        }
    }
#pragma unroll
    for (int off = 1; off < 16; off <<= 1)
#pragma unroll
        for (int r = 0; r < 4; r++) sm[r] += __shfl_xor(sm[r], off, 16);

    __syncthreads();  // fence Ps u16 stores vs bf16x8 loads (all waves)

    // ---- O = P V (K-dim padded to 160 with zeros) ----
    f32x4_t oa[2];
    oa[0] = (f32x4_t){0.f, 0.f, 0.f, 0.f};
    oa[1] = (f32x4_t){0.f, 0.f, 0.f, 0.f};
#pragma unroll
    for (int kk = 0; kk < 5; kk++) {
        bf16x8_t aP = *(const bf16x8_t*)(Ps + (wave * 16 + l16) * 168 + kk * 32 + quad * 8);
#pragma unroll
        for (int nt = 0; nt < 2; nt++) {
            int er = nt * 16 + l16;
            int sw = (er >> 3) << 3;
            bf16x8_t bV = *(const bf16x8_t*)(Vt + er * 168 + ((kk * 32 + quad * 8) ^ sw));
            oa[nt] = MFMA16(aP, bV, oa[nt]);
        }
    }
    float inv[4];
#pragma unroll
    for (int r = 0; r < 4; r++) inv[r] = 1.0f / sm[r];  // sm >= 1 (max term)
#pragma unroll
    for (int nt = 0; nt < 2; nt++) {
        int e = nt * 16 + l16;
#pragma unroll
        for (int r = 0; r < 4; r++) {
            int q = wave * 16 + quad * 4 + r;
            int qy = q >> 3, qx = q & 7;
            size_t pix = (size_t)(b * 4096) + (wi * 8 + qy) * 64 + (wj * 8 + qx);
            Op[pix * 256 + head * 32 + e] = f2bf(oa[nt][r] * inv[r]);
        }
    }
}

// ---------------------------------------------------------------------------
// Shared 128x128 GEMM mainloop (used by gemm_out).
// Staging via global_load_lds, pre-swizzled global source (see gemm_qkv).
// ---------------------------------------------------------------------------
__device__ __forceinline__ void gemm_loop(const u16* __restrict__ A,
                                          const u16* __restrict__ B,
                                          int K, int bm, int bn,
                                          u16* sA, u16* sB, f32x4_t acc[4][4]) {
    const int tid  = threadIdx.x;
    const int lane = tid & 63, wave = tid >> 6;
    const int quad = lane >> 4, l16 = lane & 15;
    const int wm = (wave >> 1) * 64, wn = (wave & 1) * 64;

    const int sub = lane >> 3;
    const int cpw = (lane & 7) ^ sub;
    const u16* gA[4]; const u16* gB[4];
    const u16* lA[4]; const u16* lB[4];
#pragma unroll
    for (int i = 0; i < 4; i++) {
        int r8 = (wave * 4 + i) * 8;
        gA[i] = A + ((size_t)(bm * 128 + r8 + sub)) * K + cpw * 8;
        gB[i] = B + ((size_t)(bn * 128 + r8 + sub)) * K + cpw * 8;
        lA[i] = sA + r8 * 64;
        lB[i] = sB + r8 * 64;
    }

    for (int kt = 0; kt < K; kt += 64) {
        __syncthreads();
#pragma unroll
        for (int i = 0; i < 4; i++) gload16(gA[i] + kt, lA[i]);
#pragma unroll
        for (int i = 0; i < 4; i++) gload16(gB[i] + kt, lB[i]);
        __syncthreads();
#pragma unroll
        for (int ks = 0; ks < 2; ks++) {
            bf16x8_t af[4], bg[4];
#pragma unroll
            for (int i = 0; i < 4; i++) {
                int row = wm + i * 16 + l16;
                int cp = (ks * 4 + quad) ^ (row & 7);
                af[i] = *(const bf16x8_t*)(sA + row * 64 + cp * 8);
            }
#pragma unroll
            for (int j = 0; j < 4; j++) {
                int row = wn + j * 16 + l16;
                int cp = (ks * 4 + quad) ^ (row & 7);
                bg[j] = *(const bf16x8_t*)(sB + row * 64 + cp * 8);
            }
#pragma unroll
            for (int i = 0; i < 4; i++)
#pragma unroll
                for (int j = 0; j < 4; j++)
                    acc[i][j] = MFMA16(af[i], bg[j], acc[i][j]);
        }
    }
}

// ---------------------------------------------------------------------------
// Kernel 3: y = attn @ W2^T + b2 -> d_out [b][c'][hw]; fp32 if fp32 inputs.
// ---------------------------------------------------------------------------
__global__ __launch_bounds__(256) void gemm_out(const u16* __restrict__ xu,
                                                const u16* __restrict__ Ap,
                                                const u16* __restrict__ W2,
                                                const u16* __restrict__ b2,
                                                void* __restrict__ Y) {
    __shared__ __align__(16) u16 sA[128 * 64];
    __shared__ __align__(16) u16 sB[128 * 64];
    __shared__ int wcnt[4];
    const u32 out_f32 = detect_fp32(xu, threadIdx.x, wcnt);

    f32x4_t acc[4][4];
    const f32x4_t zz = {0.f, 0.f, 0.f, 0.f};
#pragma unroll
    for (int i = 0; i < 4; i++)
#pragma unroll
        for (int j = 0; j < 4; j++) acc[i][j] = zz;

    const int bm = blockIdx.x, bn = blockIdx.y;
    gemm_loop(Ap, W2, 256, bm, bn, sA, sB, acc);

    const int lane = threadIdx.x & 63, wave = threadIdx.x >> 6;
    const int quad = lane >> 4, l16 = lane & 15;
    const int wm = (wave >> 1) * 64, wn = (wave & 1) * 64;
    const int b = bm >> 5;
    const int hw0 = (bm & 31) * 128;
#pragma unroll
    for (int j = 0; j < 4; j++) {
        int o = bn * 128 + wn + j * 16 + l16;
        float bias = bf2f(b2[o]);
        size_t base = ((size_t)(b * 256 + o)) * 4096;
        if (out_f32) {
            float* Yf = (float*)Y;
#pragma unroll
            for (int i = 0; i < 4; i++) {
                int m0 = hw0 + wm + i * 16 + quad * 4;
                f32x4_t ov;
#pragma unroll
                for (int r = 0; r < 4; r++) ov[r] = acc[i][j][r] + bias;
                *(f32x4_t*)(Yf + base + m0) = ov;
            }
        } else {
            u16* Yh = (u16*)Y;
#pragma unroll
            for (int i = 0; i < 4; i++) {
                int m0 = hw0 + wm + i * 16 + quad * 4;
                u32 lo = (u32)f2bf(acc[i][j][0] + bias) | ((u32)f2bf(acc[i][j][1] + bias) << 16);
                u32 hi = (u32)f2bf(acc[i][j][2] + bias) | ((u32)f2bf(acc[i][j][3] + bias) << 16);
                u32* d32 = (u32*)(Yh + base + m0);
                d32[0] = lo; d32[1] = hi;
            }
        }
    }
}

// ---------------------------------------------------------------------------
extern "C" void kernel_launch(void* const* d_in, const int* in_sizes, int n_in,
                              void* d_out, int out_size, void* d_ws, size_t ws_size,
                              hipStream_t stream) {
    (void)in_sizes; (void)n_in; (void)out_size; (void)ws_size;
    const void* x  = d_in[0];
    const void* W1 = d_in[1];
    const void* b1 = d_in[2];
    const void* W2 = d_in[3];
    const void* b2 = d_in[4];
    const u16* xu = (const u16*)x;

    char* ws = (char*)d_ws;
    const size_t MB32 = (size_t)32 * 1024 * 1024;
    u16* xT  = (u16*)(ws);              // 32 MiB; reused as attention output Op
    u16* Q2  = (u16*)(ws + MB32);       // 32 MiB  [b][head][hw][e]
    u16* K2  = (u16*)(ws + 2 * MB32);   // 32 MiB
    u16* V2  = (u16*)(ws + 3 * MB32);   // 32 MiB
    u16* W1b = (u16*)(ws + 4 * MB32);   // 196608 elems
    u16* b1b = W1b + 196608;            // 768
    u16* W2b = b1b + 768;               // 65536
    u16* b2b = W2b + 65536;             // 256
    u16* Op  = xT;                      // overlay: xT dead after gemm_qkv

    conv_w  <<<1028, 256, 0, stream>>>(xu, W1, b1, W2, b2, W1b, b1b, W2b, b2b);
    conv_x  <<<dim3(64, 4, 16), 256, 0, stream>>>(x, xT);
    gemm_qkv<<<4096, 256, 0, stream>>>(xT, W1b, b1b, Q2, K2, V2);
    attn_kernel<<<dim3(64, 8, 16), 256, 0, stream>>>(Q2, K2, V2, Op);
    gemm_out<<<dim3(512, 2), 256, 0, stream>>>(xu, Op, W2b, b2b, d_out);
}

// Round 4
// 237.942 us; speedup vs baseline: 1.0254x; 1.0254x over previous
//
#include <hip/hip_runtime.h>
#include <stdint.h>

typedef unsigned short u16;
typedef unsigned int   u32;
typedef __bf16 bf16x8_t __attribute__((ext_vector_type(8)));
typedef float  f32x4_t  __attribute__((ext_vector_type(4)));

#define MFMA16(a, b, c) __builtin_amdgcn_mfma_f32_16x16x32_bf16((a), (b), (c), 0, 0, 0)

__device__ __forceinline__ float bf2f(u16 u) {
    union { u32 i; float f; } c; c.i = ((u32)u) << 16; return c.f;
}
__device__ __forceinline__ u16 f2bf(float f) {
    union { float f; u32 i; } c; c.f = f;
    u32 x = c.i;
    return (u16)((x + 0x7fffu + ((x >> 16) & 1u)) >> 16);  // RNE
}

// Direct global->LDS DMA, 16B per lane. LDS dest must be wave-uniform base
// (HW adds lane*16); global src is per-lane (carries the XOR swizzle).
typedef const unsigned int __attribute__((address_space(1)))* gas_t;
typedef unsigned int __attribute__((address_space(3)))* las_t;
__device__ __forceinline__ void gload16(const u16* g, const u16* l) {
    __builtin_amdgcn_global_load_lds((gas_t)(const void*)g, (las_t)(void*)l, 16, 0, 0);
}

// ---------------------------------------------------------------------------
// Block-local input-dtype detection (flag=1 -> fp32 inputs).
// ---------------------------------------------------------------------------
__device__ __forceinline__ u32 detect_fp32(const u16* __restrict__ xu,
                                           int tid, int* wcnt) {
    u16 w = xu[2 * tid];
    int e = (w >> 7) & 0xff;
    int ok = (e >= 80 && e <= 160) ? 1 : 0;
    unsigned long long m = __ballot(ok);
    if ((tid & 63) == 0) wcnt[tid >> 6] = __popcll(m);
    __syncthreads();
    int cnt = wcnt[0] + wcnt[1] + wcnt[2] + wcnt[3];
    return (cnt < 160) ? 1u : 0u;
}

// ---------------------------------------------------------------------------
// Kernel W: convert W1/b1/W2/b2 to bf16 copies in workspace.
// W1/b1 rows are PERMUTED to grouped-QKV: new row h*96 + w*32 + e comes from
// original row 3*(h*32+e) + w.  This makes gemm_qkv's 96-wide tile produce
// [Q 0..31 | K 32..63 | V 64..95] directly (vectorizable repack).
// ---------------------------------------------------------------------------
__global__ __launch_bounds__(256) void conv_w(const u16* __restrict__ xu,
                                              const void* __restrict__ W1,
                                              const void* __restrict__ b1,
                                              const void* __restrict__ W2,
                                              const void* __restrict__ b2,
                                              u16* __restrict__ W1b,
                                              u16* __restrict__ b1b,
                                              u16* __restrict__ W2b,
                                              u16* __restrict__ b2b) {
    __shared__ int wcnt[4];
    u32 f = detect_fp32(xu, threadIdx.x, wcnt);
    int i = blockIdx.x * 256 + threadIdx.x;
    const int n1 = 196608, n2 = 768, n3 = 65536;
    if (i < n1) {
        int o = i >> 8, col = i & 255;
        int h = o / 96, rem = o - h * 96;
        int w = rem >> 5, e = rem & 31;
        int src = (3 * (h * 32 + e) + w) * 256 + col;
        W1b[i] = f ? f2bf(((const float*)W1)[src]) : ((const u16*)W1)[src];
    } else if (i < n1 + n2) {
        int o = i - n1;
        int h = o / 96, rem = o - h * 96;
        int w = rem >> 5, e = rem & 31;
        int src = 3 * (h * 32 + e) + w;
        b1b[o] = f ? f2bf(((const float*)b1)[src]) : ((const u16*)b1)[src];
    } else if (i < n1 + n2 + n3) {
        int li = i - n1 - n2;
        W2b[li] = f ? f2bf(((const float*)W2)[li]) : ((const u16*)W2)[li];
    } else {
        int li = i - n1 - n2 - n3;
        b2b[li] = f ? f2bf(((const float*)b2)[li]) : ((const u16*)b2)[li];
    }
}

// ---------------------------------------------------------------------------
// Kernel X: x [b][c][hw] -> xT [b*4096+hw][c] bf16 (pixel-major)
// ---------------------------------------------------------------------------
__global__ __launch_bounds__(256) void conv_x(const void* __restrict__ X,
                                              u16* __restrict__ XT) {
    __shared__ __align__(16) u16 tile[64][68];
    __shared__ int wcnt[4];
    const int tid = threadIdx.x;
    u32 f = detect_fp32((const u16*)X, tid, wcnt);
    const int b = blockIdx.z, c0 = blockIdx.y * 64, h0 = blockIdx.x * 64;
    const int col = tid & 63, rq = tid >> 6;
    if (f) {
        const float* Xf = (const float*)X;
#pragma unroll
        for (int i = 0; i < 16; i++) {
            int row = i * 4 + rq;
            tile[row][col] = f2bf(Xf[((size_t)(b * 256 + c0 + row)) * 4096 + h0 + col]);
        }
    } else {
        const u16* Xh = (const u16*)X;
#pragma unroll
        for (int i = 0; i < 16; i++) {
            int row = i * 4 + rq;
            tile[row][col] = Xh[((size_t)(b * 256 + c0 + row)) * 4096 + h0 + col];
        }
    }
    __syncthreads();
#pragma unroll
    for (int i = 0; i < 16; i++) {
        int row = i * 4 + rq;
        XT[((size_t)(b * 4096 + h0 + row)) * 256 + c0 + col] = tile[col][row];
    }
}

// ---------------------------------------------------------------------------
// Kernel 1: qkv = xT @ W1^T + b1 with 96-wide n-tiles (= one head exactly).
// W1b rows grouped [Q|K|V] per head (see conv_w) -> acc cols j0-1=Q, j2-3=K,
// j4-5=V.  Epilogue: Cs roundtrip then VECTOR b128 repack (no scalar gather).
// ---------------------------------------------------------------------------
__global__ __launch_bounds__(256) void gemm_qkv(const u16* __restrict__ XT,
                                                const u16* __restrict__ W1,
                                                const u16* __restrict__ b1,
                                                u16* __restrict__ Q2,
                                                u16* __restrict__ K2,
                                                u16* __restrict__ V2) {
    __shared__ __align__(16) u16 smem[128 * 64 + 96 * 64];  // 28 KB
    u16* sA = smem;
    u16* sB = smem + 128 * 64;
    u16* Cs = smem;  // reused after barrier: 128 x 104 = 13312 <= 14336

    const int tid  = threadIdx.x;
    const int lane = tid & 63, wave = tid >> 6;
    const int quad = lane >> 4, l16 = lane & 15;
    const int wm = wave * 32;
    const int bx = blockIdx.x;
    const int bm = (bx >> 6) * 8 + (bx & 7);  // 512 m-tiles
    const int h  = (bx >> 3) & 7;             // 8 heads
    const int o_base = h * 96;

    f32x4_t acc[2][6];
    const f32x4_t zz = {0.f, 0.f, 0.f, 0.f};
#pragma unroll
    for (int i = 0; i < 2; i++)
#pragma unroll
        for (int j = 0; j < 6; j++) acc[i][j] = zz;

    // per-lane pre-swizzled staging addresses (k-invariant, hoisted)
    const int sub = lane >> 3;              // row-within-8
    const int cpw = (lane & 7) ^ sub;       // global chunk for this lane
    const u16* gA[4]; const u16* gB[3];
    const u16* lA[4]; const u16* lB[3];
#pragma unroll
    for (int i = 0; i < 4; i++) {
        int r8 = (wave * 4 + i) * 8;
        gA[i] = XT + ((size_t)(bm * 128 + r8 + sub)) * 256 + cpw * 8;
        lA[i] = sA + r8 * 64;               // wave-uniform LDS base
    }
#pragma unroll
    for (int i = 0; i < 3; i++) {
        int r8 = (wave * 3 + i) * 8;
        gB[i] = W1 + ((size_t)(o_base + r8 + sub)) * 256 + cpw * 8;
        lB[i] = sB + r8 * 64;
    }

    for (int kt = 0; kt < 256; kt += 64) {
        __syncthreads();
#pragma unroll
        for (int i = 0; i < 4; i++) gload16(gA[i] + kt, lA[i]);
#pragma unroll
        for (int i = 0; i < 3; i++) gload16(gB[i] + kt, lB[i]);
        __syncthreads();  // implicit vmcnt(0) drains the DMA
#pragma unroll
        for (int ks = 0; ks < 2; ks++) {
            bf16x8_t af[2], bg[6];
#pragma unroll
            for (int i = 0; i < 2; i++) {
                int row = wm + i * 16 + l16;
                int cp = (ks * 4 + quad) ^ (row & 7);
                af[i] = *(const bf16x8_t*)(sA + row * 64 + cp * 8);
            }
#pragma unroll
            for (int j = 0; j < 6; j++) {
                int row = j * 16 + l16;
                int cp = (ks * 4 + quad) ^ (row & 7);
                bg[j] = *(const bf16x8_t*)(sB + row * 64 + cp * 8);
            }
#pragma unroll
            for (int i = 0; i < 2; i++)
#pragma unroll
                for (int j = 0; j < 6; j++)
                    acc[i][j] = MFMA16(af[i], bg[j], acc[i][j]);
        }
    }

    // ---- epilogue: bias + bf16 -> Cs[128 m][col 96] (stride 104) ----
    __syncthreads();
#pragma unroll
    for (int j = 0; j < 6; j++) {
        float bias = bf2f(b1[o_base + j * 16 + l16]);
#pragma unroll
        for (int i = 0; i < 2; i++) {
            int m = wm + i * 16 + quad * 4;
#pragma unroll
            for (int r = 0; r < 4; r++)
                Cs[(m + r) * 104 + j * 16 + l16] = f2bf(acc[i][j][r] + bias);
        }
    }
    __syncthreads();

    // ---- repack: grouped cols -> vector reads; pixel-major [b][h][hw][e] ----
    const int b = bm >> 5;
    const int hw0 = (bm & 31) * 128;
    const size_t hb = ((size_t)(b * 8 + h)) * 4096;
#pragma unroll
    for (int it = 0; it < 2; it++) {
        int u = it * 256 + tid;
        int px = u >> 2, ch = u & 3;
        size_t gaddr = (hb + hw0 + px) * 32 + ch * 8;
        *(uint4*)(Q2 + gaddr) = *(const uint4*)(Cs + px * 104 +      ch * 8);
        *(uint4*)(K2 + gaddr) = *(const uint4*)(Cs + px * 104 + 32 + ch * 8);
        *(uint4*)(V2 + gaddr) = *(const uint4*)(Cs + px * 104 + 64 + ch * 8);
    }
}

// ---------------------------------------------------------------------------
// Kernel 2: windowed overlapping attention (Q 8x8, K/V 12x12 zero-padded).
// Q straight to registers.  LDS 32256 B.
// V staging uses lane map ch=u/144, px=u%144 so each write instruction's
// colp spans 64 consecutive cols -> all 32 banks, 2-way (free) instead of
// the old 8-way conflict (bank = 84e + colp/2 mod 32; 8-row e term == 0).
// ---------------------------------------------------------------------------
__global__ __launch_bounds__(256) void attn_kernel(const u16* __restrict__ Q2,
                                                   const u16* __restrict__ K2,
                                                   const u16* __restrict__ V2,
                                                   u16* __restrict__ Op) {
    __shared__ __align__(16) u16 smem[16128];  // 32256 B
    u16* Ks = smem;               // [k][e]    stride 40   (dead after QK^T)
    u16* Ps = smem;               // [q][k]    stride 168  (overlay)
    u16* Vt = smem + 10752;       // [e][k]    stride 168, swizzled cols

    const int tid  = threadIdx.x;
    const int lane = tid & 63, wave = tid >> 6;
    const int quad = lane >> 4, l16 = lane & 15;
    const int win = blockIdx.x, head = blockIdx.y, b = blockIdx.z;
    const int wi = win >> 3, wj = win & 7;
    const size_t hb = ((size_t)(b * 8 + head)) * 4096;

    // ---- Q straight to register: row wave*16+l16, chunk quad (16B) ----
    bf16x8_t aF;
    {
        int px = wave * 16 + l16;
        int qy = px >> 3, qx = px & 7;
        aF = *(const bf16x8_t*)(Q2 + (hb + (wi * 8 + qy) * 64 + wj * 8 + qx) * 32 + quad * 8);
    }
    // ---- stage K ----
    for (int u = tid; u < 576; u += 256) {
        int px = u >> 2, ch = u & 3;
        int py = px / 12, kx = px - py * 12;
        int gy = wi * 8 - 2 + py, gx = wj * 8 - 2 + kx;
        uint4 kv = make_uint4(0, 0, 0, 0);
        if (gy >= 0 && gy < 64 && gx >= 0 && gx < 64)
            kv = *(const uint4*)(K2 + (hb + gy * 64 + gx) * 32 + ch * 8);
        *(uint4*)(Ks + px * 40 + ch * 8) = kv;
    }
    // ---- stage V transposed w/ swizzle (conflict-free lane map) ----
    for (int u = tid; u < 576; u += 256) {
        int ch = u / 144, px = u - ch * 144;
        int py = px / 12, kx = px - py * 12;
        int gy = wi * 8 - 2 + py, gx = wj * 8 - 2 + kx;
        uint4 vv = make_uint4(0, 0, 0, 0);
        if (gy >= 0 && gy < 64 && gx >= 0 && gx < 64)
            vv = *(const uint4*)(V2 + (hb + gy * 64 + gx) * 32 + ch * 8);
        int colp = px ^ (ch << 3);
        int e0 = ch * 8;
        u32 w0[4] = {vv.x, vv.y, vv.z, vv.w};
#pragma unroll
        for (int p = 0; p < 4; p++) {
            Vt[(e0 + 2 * p    ) * 168 + colp] = (u16)(w0[p] & 0xffff);
            Vt[(e0 + 2 * p + 1) * 168 + colp] = (u16)(w0[p] >> 16);
        }
    }
    // ---- Vt pad cols 144..159 (swizzled addresses) ----
    for (int t = tid; t < 512; t += 256) {
        int e = t >> 4, cl = 144 + (t & 15);
        Vt[e * 168 + (cl ^ ((e >> 3) << 3))] = 0;
    }
    __syncthreads();

    // ---- scores: S_raw = Q K^T (wave w owns q rows 16w..16w+15) ----
    float s[9][4];
    {
        const f32x4_t zz = {0.f, 0.f, 0.f, 0.f};
#pragma unroll
        for (int j = 0; j < 9; j++) {
            bf16x8_t bF = *(const bf16x8_t*)(Ks + (j * 16 + l16) * 40 + quad * 8);
            f32x4_t d = MFMA16(aF, bF, zz);
#pragma unroll
            for (int r = 0; r < 4; r++) s[j][r] = d[r];
        }
    }
    // ---- row max on raw scores (scale folded into exp arg) ----
    float mx[4] = {-1e30f, -1e30f, -1e30f, -1e30f};
#pragma unroll
    for (int j = 0; j < 9; j++)
#pragma unroll
        for (int r = 0; r < 4; r++) mx[r] = fmaxf(mx[r], s[j][r]);
#pragma unroll
    for (int off = 1; off < 16; off <<= 1)
#pragma unroll
        for (int r = 0; r < 4; r++) mx[r] = fmaxf(mx[r], __shfl_xor(mx[r], off, 16));

    __syncthreads();  // Ks fully consumed by all waves; Ps overlay begins

    // ---- Ps pad cols 144..159 for this wave's 16 rows (one b64/lane) ----
    *(unsigned long long*)(Ps + (wave * 16 + l16) * 168 + 144 + quad * 4) = 0ULL;

    const float scale = 0.17677669529663687f;  // 1/sqrt(32)
    float msc[4];
#pragma unroll
    for (int r = 0; r < 4; r++) msc[r] = mx[r] * scale;
    float sm[4] = {0.f, 0.f, 0.f, 0.f};
#pragma unroll
    for (int j = 0; j < 9; j++) {
#pragma unroll
        for (int r = 0; r < 4; r++) {
            float p = __expf(fmaf(s[j][r], scale, -msc[r]));
            sm[r] += p;
            Ps[(wave * 16 + quad * 4 + r) * 168 + j * 16 + l16] = f2bf(p);
        }
    }
#pragma unroll
    for (int off = 1; off < 16; off <<= 1)
#pragma unroll
        for (int r = 0; r < 4; r++) sm[r] += __shfl_xor(sm[r], off, 16);

    __syncthreads();  // fence Ps u16 stores vs bf16x8 loads (all waves)

    // ---- O = P V (K-dim padded to 160 with zeros) ----
    f32x4_t oa[2];
    oa[0] = (f32x4_t){0.f, 0.f, 0.f, 0.f};
    oa[1] = (f32x4_t){0.f, 0.f, 0.f, 0.f};
#pragma unroll
    for (int kk = 0; kk < 5; kk++) {
        bf16x8_t aP = *(const bf16x8_t*)(Ps + (wave * 16 + l16) * 168 + kk * 32 + quad * 8);
#pragma unroll
        for (int nt = 0; nt < 2; nt++) {
            int er = nt * 16 + l16;
            int sw = (er >> 3) << 3;
            bf16x8_t bV = *(const bf16x8_t*)(Vt + er * 168 + ((kk * 32 + quad * 8) ^ sw));
            oa[nt] = MFMA16(aP, bV, oa[nt]);
        }
    }
    float inv[4];
#pragma unroll
    for (int r = 0; r < 4; r++) inv[r] = 1.0f / sm[r];  // sm >= 1 (max term)
#pragma unroll
    for (int nt = 0; nt < 2; nt++) {
        int e = nt * 16 + l16;
#pragma unroll
        for (int r = 0; r < 4; r++) {
            int q = wave * 16 + quad * 4 + r;
            int qy = q >> 3, qx = q & 7;
            size_t pix = (size_t)(b * 4096) + (wi * 8 + qy) * 64 + (wj * 8 + qx);
            Op[pix * 256 + head * 32 + e] = f2bf(oa[nt][r] * inv[r]);
        }
    }
}

// ---------------------------------------------------------------------------
// Shared 128x128 GEMM mainloop (used by gemm_out).
// ---------------------------------------------------------------------------
__device__ __forceinline__ void gemm_loop(const u16* __restrict__ A,
                                          const u16* __restrict__ B,
                                          int K, int bm, int bn,
                                          u16* sA, u16* sB, f32x4_t acc[4][4]) {
    const int tid  = threadIdx.x;
    const int lane = tid & 63, wave = tid >> 6;
    const int quad = lane >> 4, l16 = lane & 15;
    const int wm = (wave >> 1) * 64, wn = (wave & 1) * 64;

    const int sub = lane >> 3;
    const int cpw = (lane & 7) ^ sub;
    const u16* gA[4]; const u16* gB[4];
    const u16* lA[4]; const u16* lB[4];
#pragma unroll
    for (int i = 0; i < 4; i++) {
        int r8 = (wave * 4 + i) * 8;
        gA[i] = A + ((size_t)(bm * 128 + r8 + sub)) * K + cpw * 8;
        gB[i] = B + ((size_t)(bn * 128 + r8 + sub)) * K + cpw * 8;
        lA[i] = sA + r8 * 64;
        lB[i] = sB + r8 * 64;
    }

    for (int kt = 0; kt < K; kt += 64) {
        __syncthreads();
#pragma unroll
        for (int i = 0; i < 4; i++) gload16(gA[i] + kt, lA[i]);
#pragma unroll
        for (int i = 0; i < 4; i++) gload16(gB[i] + kt, lB[i]);
        __syncthreads();
#pragma unroll
        for (int ks = 0; ks < 2; ks++) {
            bf16x8_t af[4], bg[4];
#pragma unroll
            for (int i = 0; i < 4; i++) {
                int row = wm + i * 16 + l16;
                int cp = (ks * 4 + quad) ^ (row & 7);
                af[i] = *(const bf16x8_t*)(sA + row * 64 + cp * 8);
            }
#pragma unroll
            for (int j = 0; j < 4; j++) {
                int row = wn + j * 16 + l16;
                int cp = (ks * 4 + quad) ^ (row & 7);
                bg[j] = *(const bf16x8_t*)(sB + row * 64 + cp * 8);
            }
#pragma unroll
            for (int i = 0; i < 4; i++)
#pragma unroll
                for (int j = 0; j < 4; j++)
                    acc[i][j] = MFMA16(af[i], bg[j], acc[i][j]);
        }
    }
}

// ---------------------------------------------------------------------------
// Kernel 3: y = attn @ W2^T + b2 -> d_out [b][c'][hw]; fp32 if fp32 inputs.
// ---------------------------------------------------------------------------
__global__ __launch_bounds__(256) void gemm_out(const u16* __restrict__ xu,
                                                const u16* __restrict__ Ap,
                                                const u16* __restrict__ W2,
                                                const u16* __restrict__ b2,
                                                void* __restrict__ Y) {
    __shared__ __align__(16) u16 sA[128 * 64];
    __shared__ __align__(16) u16 sB[128 * 64];
    __shared__ int wcnt[4];
    const u32 out_f32 = detect_fp32(xu, threadIdx.x, wcnt);

    f32x4_t acc[4][4];
    const f32x4_t zz = {0.f, 0.f, 0.f, 0.f};
#pragma unroll
    for (int i = 0; i < 4; i++)
#pragma unroll
        for (int j = 0; j < 4; j++) acc[i][j] = zz;

    const int bm = blockIdx.x, bn = blockIdx.y;
    gemm_loop(Ap, W2, 256, bm, bn, sA, sB, acc);

    const int lane = threadIdx.x & 63, wave = threadIdx.x >> 6;
    const int quad = lane >> 4, l16 = lane & 15;
    const int wm = (wave >> 1) * 64, wn = (wave & 1) * 64;
    const int b = bm >> 5;
    const int hw0 = (bm & 31) * 128;
#pragma unroll
    for (int j = 0; j < 4; j++) {
        int o = bn * 128 + wn + j * 16 + l16;
        float bias = bf2f(b2[o]);
        size_t base = ((size_t)(b * 256 + o)) * 4096;
        if (out_f32) {
            float* Yf = (float*)Y;
#pragma unroll
            for (int i = 0; i < 4; i++) {
                int m0 = hw0 + wm + i * 16 + quad * 4;
                f32x4_t ov;
#pragma unroll
                for (int r = 0; r < 4; r++) ov[r] = acc[i][j][r] + bias;
                *(f32x4_t*)(Yf + base + m0) = ov;
            }
        } else {
            u16* Yh = (u16*)Y;
#pragma unroll
            for (int i = 0; i < 4; i++) {
                int m0 = hw0 + wm + i * 16 + quad * 4;
                u32 lo = (u32)f2bf(acc[i][j][0] + bias) | ((u32)f2bf(acc[i][j][1] + bias) << 16);
                u32 hi = (u32)f2bf(acc[i][j][2] + bias) | ((u32)f2bf(acc[i][j][3] + bias) << 16);
                u32* d32 = (u32*)(Yh + base + m0);
                d32[0] = lo; d32[1] = hi;
            }
        }
    }
}

// ---------------------------------------------------------------------------
extern "C" void kernel_launch(void* const* d_in, const int* in_sizes, int n_in,
                              void* d_out, int out_size, void* d_ws, size_t ws_size,
                              hipStream_t stream) {
    (void)in_sizes; (void)n_in; (void)out_size; (void)ws_size;
    const void* x  = d_in[0];
    const void* W1 = d_in[1];
    const void* b1 = d_in[2];
    const void* W2 = d_in[3];
    const void* b2 = d_in[4];
    const u16* xu = (const u16*)x;

    char* ws = (char*)d_ws;
    const size_t MB32 = (size_t)32 * 1024 * 1024;
    u16* xT  = (u16*)(ws);              // 32 MiB; reused as attention output Op
    u16* Q2  = (u16*)(ws + MB32);       // 32 MiB  [b][head][hw][e]
    u16* K2  = (u16*)(ws + 2 * MB32);   // 32 MiB
    u16* V2  = (u16*)(ws + 3 * MB32);   // 32 MiB
    u16* W1b = (u16*)(ws + 4 * MB32);   // 196608 elems (grouped-QKV rows)
    u16* b1b = W1b + 196608;            // 768
    u16* W2b = b1b + 768;               // 65536
    u16* b2b = W2b + 65536;             // 256
    u16* Op  = xT;                      // overlay: xT dead after gemm_qkv

    conv_w  <<<1028, 256, 0, stream>>>(xu, W1, b1, W2, b2, W1b, b1b, W2b, b2b);
    conv_x  <<<dim3(64, 4, 16), 256, 0, stream>>>(x, xT);
    gemm_qkv<<<4096, 256, 0, stream>>>(xT, W1b, b1b, Q2, K2, V2);
    attn_kernel<<<dim3(64, 8, 16), 256, 0, stream>>>(Q2, K2, V2, Op);
    gemm_out<<<dim3(512, 2), 256, 0, stream>>>(xu, Op, W2b, b2b, d_out);
}

// Round 5
// 234.207 us; speedup vs baseline: 1.0418x; 1.0159x over previous
//
#include <hip/hip_runtime.h>
#include <stdint.h>

typedef unsigned short u16;
typedef unsigned int   u32;
typedef __bf16 bf16x8_t __attribute__((ext_vector_type(8)));
typedef float  f32x4_t  __attribute__((ext_vector_type(4)));

#define MFMA16(a, b, c) __builtin_amdgcn_mfma_f32_16x16x32_bf16((a), (b), (c), 0, 0, 0)

__device__ __forceinline__ float bf2f(u16 u) {
    union { u32 i; float f; } c; c.i = ((u32)u) << 16; return c.f;
}
__device__ __forceinline__ u16 f2bf(float f) {
    union { float f; u32 i; } c; c.f = f;
    u32 x = c.i;
    return (u16)((x + 0x7fffu + ((x >> 16) & 1u)) >> 16);  // RNE
}

// Direct global->LDS DMA, 16B per lane. LDS dest must be wave-uniform base
// (HW adds lane*16); global src is per-lane (carries the XOR swizzle).
typedef const unsigned int __attribute__((address_space(1)))* gas_t;
typedef unsigned int __attribute__((address_space(3)))* las_t;
__device__ __forceinline__ void gload16(const u16* g, const u16* l) {
    __builtin_amdgcn_global_load_lds((gas_t)(const void*)g, (las_t)(void*)l, 16, 0, 0);
}

// ---------------------------------------------------------------------------
// Block-local input-dtype detection (flag=1 -> fp32 inputs).
// ---------------------------------------------------------------------------
__device__ __forceinline__ u32 detect_fp32(const u16* __restrict__ xu,
                                           int tid, int* wcnt) {
    u16 w = xu[2 * tid];
    int e = (w >> 7) & 0xff;
    int ok = (e >= 80 && e <= 160) ? 1 : 0;
    unsigned long long m = __ballot(ok);
    if ((tid & 63) == 0) wcnt[tid >> 6] = __popcll(m);
    __syncthreads();
    int cnt = wcnt[0] + wcnt[1] + wcnt[2] + wcnt[3];
    return (cnt < 160) ? 1u : 0u;
}

// ---------------------------------------------------------------------------
// Kernel W: convert W1/b1/W2/b2 to bf16 copies in workspace.
// W1/b1 rows are PERMUTED to grouped-QKV: new row h*96 + w*32 + e comes from
// original row 3*(h*32+e) + w.  This makes gemm_qkv's 96-wide tile produce
// [Q 0..31 | K 32..63 | V 64..95] directly (vectorizable repack).
// ---------------------------------------------------------------------------
__global__ __launch_bounds__(256) void conv_w(const u16* __restrict__ xu,
                                              const void* __restrict__ W1,
                                              const void* __restrict__ b1,
                                              const void* __restrict__ W2,
                                              const void* __restrict__ b2,
                                              u16* __restrict__ W1b,
                                              u16* __restrict__ b1b,
                                              u16* __restrict__ W2b,
                                              u16* __restrict__ b2b) {
    __shared__ int wcnt[4];
    u32 f = detect_fp32(xu, threadIdx.x, wcnt);
    int i = blockIdx.x * 256 + threadIdx.x;
    const int n1 = 196608, n2 = 768, n3 = 65536;
    if (i < n1) {
        int o = i >> 8, col = i & 255;
        int h = o / 96, rem = o - h * 96;
        int w = rem >> 5, e = rem & 31;
        int src = (3 * (h * 32 + e) + w) * 256 + col;
        W1b[i] = f ? f2bf(((const float*)W1)[src]) : ((const u16*)W1)[src];
    } else if (i < n1 + n2) {
        int o = i - n1;
        int h = o / 96, rem = o - h * 96;
        int w = rem >> 5, e = rem & 31;
        int src = 3 * (h * 32 + e) + w;
        b1b[o] = f ? f2bf(((const float*)b1)[src]) : ((const u16*)b1)[src];
    } else if (i < n1 + n2 + n3) {
        int li = i - n1 - n2;
        W2b[li] = f ? f2bf(((const float*)W2)[li]) : ((const u16*)W2)[li];
    } else {
        int li = i - n1 - n2 - n3;
        b2b[li] = f ? f2bf(((const float*)b2)[li]) : ((const u16*)b2)[li];
    }
}

// ---------------------------------------------------------------------------
// Kernel X: x [b][c][hw] -> xT [b*4096+hw][c] bf16 (pixel-major)
// ---------------------------------------------------------------------------
__global__ __launch_bounds__(256) void conv_x(const void* __restrict__ X,
                                              u16* __restrict__ XT) {
    __shared__ __align__(16) u16 tile[64][68];
    __shared__ int wcnt[4];
    const int tid = threadIdx.x;
    u32 f = detect_fp32((const u16*)X, tid, wcnt);
    const int b = blockIdx.z, c0 = blockIdx.y * 64, h0 = blockIdx.x * 64;
    const int col = tid & 63, rq = tid >> 6;
    if (f) {
        const float* Xf = (const float*)X;
#pragma unroll
        for (int i = 0; i < 16; i++) {
            int row = i * 4 + rq;
            tile[row][col] = f2bf(Xf[((size_t)(b * 256 + c0 + row)) * 4096 + h0 + col]);
        }
    } else {
        const u16* Xh = (const u16*)X;
#pragma unroll
        for (int i = 0; i < 16; i++) {
            int row = i * 4 + rq;
            tile[row][col] = Xh[((size_t)(b * 256 + c0 + row)) * 4096 + h0 + col];
        }
    }
    __syncthreads();
#pragma unroll
    for (int i = 0; i < 16; i++) {
        int row = i * 4 + rq;
        XT[((size_t)(b * 4096 + h0 + row)) * 256 + c0 + col] = tile[col][row];
    }
}

// ---------------------------------------------------------------------------
// Kernel 1: qkv = xT @ W1^T + b1 with 96-wide n-tiles (= one head exactly).
// W1b rows grouped [Q|K|V] per head (see conv_w) -> acc cols j0-1=Q, j2-3=K,
// j4-5=V.  Epilogue: Cs roundtrip then VECTOR b128 repack (no scalar gather).
// ---------------------------------------------------------------------------
__global__ __launch_bounds__(256) void gemm_qkv(const u16* __restrict__ XT,
                                                const u16* __restrict__ W1,
                                                const u16* __restrict__ b1,
                                                u16* __restrict__ Q2,
                                                u16* __restrict__ K2,
                                                u16* __restrict__ V2) {
    __shared__ __align__(16) u16 smem[128 * 64 + 96 * 64];  // 28 KB
    u16* sA = smem;
    u16* sB = smem + 128 * 64;
    u16* Cs = smem;  // reused after barrier: 128 x 104 = 13312 <= 14336

    const int tid  = threadIdx.x;
    const int lane = tid & 63, wave = tid >> 6;
    const int quad = lane >> 4, l16 = lane & 15;
    const int wm = wave * 32;
    const int bx = blockIdx.x;
    const int bm = (bx >> 6) * 8 + (bx & 7);  // 512 m-tiles
    const int h  = (bx >> 3) & 7;             // 8 heads
    const int o_base = h * 96;

    f32x4_t acc[2][6];
    const f32x4_t zz = {0.f, 0.f, 0.f, 0.f};
#pragma unroll
    for (int i = 0; i < 2; i++)
#pragma unroll
        for (int j = 0; j < 6; j++) acc[i][j] = zz;

    // per-lane pre-swizzled staging addresses (k-invariant, hoisted)
    const int sub = lane >> 3;              // row-within-8
    const int cpw = (lane & 7) ^ sub;       // global chunk for this lane
    const u16* gA[4]; const u16* gB[3];
    const u16* lA[4]; const u16* lB[3];
#pragma unroll
    for (int i = 0; i < 4; i++) {
        int r8 = (wave * 4 + i) * 8;
        gA[i] = XT + ((size_t)(bm * 128 + r8 + sub)) * 256 + cpw * 8;
        lA[i] = sA + r8 * 64;               // wave-uniform LDS base
    }
#pragma unroll
    for (int i = 0; i < 3; i++) {
        int r8 = (wave * 3 + i) * 8;
        gB[i] = W1 + ((size_t)(o_base + r8 + sub)) * 256 + cpw * 8;
        lB[i] = sB + r8 * 64;
    }

    for (int kt = 0; kt < 256; kt += 64) {
        __syncthreads();
#pragma unroll
        for (int i = 0; i < 4; i++) gload16(gA[i] + kt, lA[i]);
#pragma unroll
        for (int i = 0; i < 3; i++) gload16(gB[i] + kt, lB[i]);
        __syncthreads();  // implicit vmcnt(0) drains the DMA
#pragma unroll
        for (int ks = 0; ks < 2; ks++) {
            bf16x8_t af[2], bg[6];
#pragma unroll
            for (int i = 0; i < 2; i++) {
                int row = wm + i * 16 + l16;
                int cp = (ks * 4 + quad) ^ (row & 7);
                af[i] = *(const bf16x8_t*)(sA + row * 64 + cp * 8);
            }
#pragma unroll
            for (int j = 0; j < 6; j++) {
                int row = j * 16 + l16;
                int cp = (ks * 4 + quad) ^ (row & 7);
                bg[j] = *(const bf16x8_t*)(sB + row * 64 + cp * 8);
            }
#pragma unroll
            for (int i = 0; i < 2; i++)
#pragma unroll
                for (int j = 0; j < 6; j++)
                    acc[i][j] = MFMA16(af[i], bg[j], acc[i][j]);
        }
    }

    // ---- epilogue: bias + bf16 -> Cs[128 m][col 96] (stride 104) ----
    __syncthreads();
#pragma unroll
    for (int j = 0; j < 6; j++) {
        float bias = bf2f(b1[o_base + j * 16 + l16]);
#pragma unroll
        for (int i = 0; i < 2; i++) {
            int m = wm + i * 16 + quad * 4;
#pragma unroll
            for (int r = 0; r < 4; r++)
                Cs[(m + r) * 104 + j * 16 + l16] = f2bf(acc[i][j][r] + bias);
        }
    }
    __syncthreads();

    // ---- repack: grouped cols -> vector reads; pixel-major [b][h][hw][e] ----
    const int b = bm >> 5;
    const int hw0 = (bm & 31) * 128;
    const size_t hb = ((size_t)(b * 8 + h)) * 4096;
#pragma unroll
    for (int it = 0; it < 2; it++) {
        int u = it * 256 + tid;
        int px = u >> 2, ch = u & 3;
        size_t gaddr = (hb + hw0 + px) * 32 + ch * 8;
        *(uint4*)(Q2 + gaddr) = *(const uint4*)(Cs + px * 104 +      ch * 8);
        *(uint4*)(K2 + gaddr) = *(const uint4*)(Cs + px * 104 + 32 + ch * 8);
        *(uint4*)(V2 + gaddr) = *(const uint4*)(Cs + px * 104 + 64 + ch * 8);
    }
}

// ---------------------------------------------------------------------------
// Kernel 2: windowed overlapping attention (Q 8x8, K/V 12x12 zero-padded).
// Q straight to registers.  LDS 32256 B -> 5 blocks/CU.
// K+V staged in one merged loop (px=u>>2, ch=u&3: 4 lanes cover one full
// 64B pixel -> fully coalesced global reads).  V transposed w/ XOR swizzle.
// ---------------------------------------------------------------------------
__global__ __launch_bounds__(256) void attn_kernel(const u16* __restrict__ Q2,
                                                   const u16* __restrict__ K2,
                                                   const u16* __restrict__ V2,
                                                   u16* __restrict__ Op) {
    __shared__ __align__(16) u16 smem[16128];  // 32256 B
    u16* Ks = smem;               // [k][e]    stride 40   (dead after QK^T)
    u16* Ps = smem;               // [q][k]    stride 168  (overlay)
    u16* Vt = smem + 10752;       // [e][k]    stride 168, swizzled cols

    const int tid  = threadIdx.x;
    const int lane = tid & 63, wave = tid >> 6;
    const int quad = lane >> 4, l16 = lane & 15;
    const int win = blockIdx.x, head = blockIdx.y, b = blockIdx.z;
    const int wi = win >> 3, wj = win & 7;
    const size_t hb = ((size_t)(b * 8 + head)) * 4096;

    // ---- Q straight to register: row wave*16+l16, chunk quad (16B) ----
    bf16x8_t aF;
    {
        int px = wave * 16 + l16;
        int qy = px >> 3, qx = px & 7;
        aF = *(const bf16x8_t*)(Q2 + (hb + (wi * 8 + qy) * 64 + wj * 8 + qx) * 32 + quad * 8);
    }
    // ---- stage K + V (merged, one addr calc); V transposed w/ swizzle ----
    for (int u = tid; u < 576; u += 256) {
        int px = u >> 2, ch = u & 3;
        int py = px / 12, kx = px - py * 12;
        int gy = wi * 8 - 2 + py, gx = wj * 8 - 2 + kx;
        uint4 kv = make_uint4(0, 0, 0, 0), vv = make_uint4(0, 0, 0, 0);
        if (gy >= 0 && gy < 64 && gx >= 0 && gx < 64) {
            size_t off = (hb + gy * 64 + gx) * 32 + ch * 8;
            kv = *(const uint4*)(K2 + off);
            vv = *(const uint4*)(V2 + off);
        }
        *(uint4*)(Ks + px * 40 + ch * 8) = kv;
        int colp = px ^ (ch << 3);
        int e0 = ch * 8;
        u32 w0[4] = {vv.x, vv.y, vv.z, vv.w};
#pragma unroll
        for (int p = 0; p < 4; p++) {
            Vt[(e0 + 2 * p    ) * 168 + colp] = (u16)(w0[p] & 0xffff);
            Vt[(e0 + 2 * p + 1) * 168 + colp] = (u16)(w0[p] >> 16);
        }
    }
    // ---- Vt pad cols 144..159 (swizzled addresses) ----
    for (int t = tid; t < 512; t += 256) {
        int e = t >> 4, cl = 144 + (t & 15);
        Vt[e * 168 + (cl ^ ((e >> 3) << 3))] = 0;
    }
    __syncthreads();

    // ---- scores: S_raw = Q K^T (wave w owns q rows 16w..16w+15) ----
    float s[9][4];
    {
        const f32x4_t zz = {0.f, 0.f, 0.f, 0.f};
#pragma unroll
        for (int j = 0; j < 9; j++) {
            bf16x8_t bF = *(const bf16x8_t*)(Ks + (j * 16 + l16) * 40 + quad * 8);
            f32x4_t d = MFMA16(aF, bF, zz);
#pragma unroll
            for (int r = 0; r < 4; r++) s[j][r] = d[r];
        }
    }
    // ---- row max on raw scores (scale folded into exp arg) ----
    float mx[4] = {-1e30f, -1e30f, -1e30f, -1e30f};
#pragma unroll
    for (int j = 0; j < 9; j++)
#pragma unroll
        for (int r = 0; r < 4; r++) mx[r] = fmaxf(mx[r], s[j][r]);
#pragma unroll
    for (int off = 1; off < 16; off <<= 1)
#pragma unroll
        for (int r = 0; r < 4; r++) mx[r] = fmaxf(mx[r], __shfl_xor(mx[r], off, 16));

    __syncthreads();  // Ks fully consumed by all waves; Ps overlay begins

    // ---- Ps pad cols 144..159 for this wave's 16 rows (one b64/lane) ----
    *(unsigned long long*)(Ps + (wave * 16 + l16) * 168 + 144 + quad * 4) = 0ULL;

    const float scale = 0.17677669529663687f;  // 1/sqrt(32)
    float msc[4];
#pragma unroll
    for (int r = 0; r < 4; r++) msc[r] = mx[r] * scale;
    float sm[4] = {0.f, 0.f, 0.f, 0.f};
#pragma unroll
    for (int j = 0; j < 9; j++) {
#pragma unroll
        for (int r = 0; r < 4; r++) {
            float p = __expf(fmaf(s[j][r], scale, -msc[r]));
            sm[r] += p;
            Ps[(wave * 16 + quad * 4 + r) * 168 + j * 16 + l16] = f2bf(p);
        }
    }
#pragma unroll
    for (int off = 1; off < 16; off <<= 1)
#pragma unroll
        for (int r = 0; r < 4; r++) sm[r] += __shfl_xor(sm[r], off, 16);

    __syncthreads();  // fence Ps u16 stores vs bf16x8 loads (all waves)

    // ---- O = P V (K-dim padded to 160 with zeros) ----
    f32x4_t oa[2];
    oa[0] = (f32x4_t){0.f, 0.f, 0.f, 0.f};
    oa[1] = (f32x4_t){0.f, 0.f, 0.f, 0.f};
#pragma unroll
    for (int kk = 0; kk < 5; kk++) {
        bf16x8_t aP = *(const bf16x8_t*)(Ps + (wave * 16 + l16) * 168 + kk * 32 + quad * 8);
#pragma unroll
        for (int nt = 0; nt < 2; nt++) {
            int er = nt * 16 + l16;
            int sw = (er >> 3) << 3;
            bf16x8_t bV = *(const bf16x8_t*)(Vt + er * 168 + ((kk * 32 + quad * 8) ^ sw));
            oa[nt] = MFMA16(aP, bV, oa[nt]);
        }
    }
    float inv[4];
#pragma unroll
    for (int r = 0; r < 4; r++) inv[r] = 1.0f / sm[r];  // sm >= 1 (max term)
#pragma unroll
    for (int nt = 0; nt < 2; nt++) {
        int e = nt * 16 + l16;
#pragma unroll
        for (int r = 0; r < 4; r++) {
            int q = wave * 16 + quad * 4 + r;
            int qy = q >> 3, qx = q & 7;
            size_t pix = (size_t)(b * 4096) + (wi * 8 + qy) * 64 + (wj * 8 + qx);
            Op[pix * 256 + head * 32 + e] = f2bf(oa[nt][r] * inv[r]);
        }
    }
}

// ---------------------------------------------------------------------------
// Shared 128x128 GEMM mainloop (used by gemm_out).
// ---------------------------------------------------------------------------
__device__ __forceinline__ void gemm_loop(const u16* __restrict__ A,
                                          const u16* __restrict__ B,
                                          int K, int bm, int bn,
                                          u16* sA, u16* sB, f32x4_t acc[4][4]) {
    const int tid  = threadIdx.x;
    const int lane = tid & 63, wave = tid >> 6;
    const int quad = lane >> 4, l16 = lane & 15;
    const int wm = (wave >> 1) * 64, wn = (wave & 1) * 64;

    const int sub = lane >> 3;
    const int cpw = (lane & 7) ^ sub;
    const u16* gA[4]; const u16* gB[4];
    const u16* lA[4]; const u16* lB[4];
#pragma unroll
    for (int i = 0; i < 4; i++) {
        int r8 = (wave * 4 + i) * 8;
        gA[i] = A + ((size_t)(bm * 128 + r8 + sub)) * K + cpw * 8;
        gB[i] = B + ((size_t)(bn * 128 + r8 + sub)) * K + cpw * 8;
        lA[i] = sA + r8 * 64;
        lB[i] = sB + r8 * 64;
    }

    for (int kt = 0; kt < K; kt += 64) {
        __syncthreads();
#pragma unroll
        for (int i = 0; i < 4; i++) gload16(gA[i] + kt, lA[i]);
#pragma unroll
        for (int i = 0; i < 4; i++) gload16(gB[i] + kt, lB[i]);
        __syncthreads();
#pragma unroll
        for (int ks = 0; ks < 2; ks++) {
            bf16x8_t af[4], bg[4];
#pragma unroll
            for (int i = 0; i < 4; i++) {
                int row = wm + i * 16 + l16;
                int cp = (ks * 4 + quad) ^ (row & 7);
                af[i] = *(const bf16x8_t*)(sA + row * 64 + cp * 8);
            }
#pragma unroll
            for (int j = 0; j < 4; j++) {
                int row = wn + j * 16 + l16;
                int cp = (ks * 4 + quad) ^ (row & 7);
                bg[j] = *(const bf16x8_t*)(sB + row * 64 + cp * 8);
            }
#pragma unroll
            for (int i = 0; i < 4; i++)
#pragma unroll
                for (int j = 0; j < 4; j++)
                    acc[i][j] = MFMA16(af[i], bg[j], acc[i][j]);
        }
    }
}

// ---------------------------------------------------------------------------
// Kernel 3: y = attn @ W2^T + b2 -> d_out [b][c'][hw]; fp32 if fp32 inputs.
// ---------------------------------------------------------------------------
__global__ __launch_bounds__(256) void gemm_out(const u16* __restrict__ xu,
                                                const u16* __restrict__ Ap,
                                                const u16* __restrict__ W2,
                                                const u16* __restrict__ b2,
                                                void* __restrict__ Y) {
    __shared__ __align__(16) u16 sA[128 * 64];
    __shared__ __align__(16) u16 sB[128 * 64];
    __shared__ int wcnt[4];
    const u32 out_f32 = detect_fp32(xu, threadIdx.x, wcnt);

    f32x4_t acc[4][4];
    const f32x4_t zz = {0.f, 0.f, 0.f, 0.f};
#pragma unroll
    for (int i = 0; i < 4; i++)
#pragma unroll
        for (int j = 0; j < 4; j++) acc[i][j] = zz;

    const int bm = blockIdx.x, bn = blockIdx.y;
    gemm_loop(Ap, W2, 256, bm, bn, sA, sB, acc);

    const int lane = threadIdx.x & 63, wave = threadIdx.x >> 6;
    const int quad = lane >> 4, l16 = lane & 15;
    const int wm = (wave >> 1) * 64, wn = (wave & 1) * 64;
    const int b = bm >> 5;
    const int hw0 = (bm & 31) * 128;
#pragma unroll
    for (int j = 0; j < 4; j++) {
        int o = bn * 128 + wn + j * 16 + l16;
        float bias = bf2f(b2[o]);
        size_t base = ((size_t)(b * 256 + o)) * 4096;
        if (out_f32) {
            float* Yf = (float*)Y;
#pragma unroll
            for (int i = 0; i < 4; i++) {
                int m0 = hw0 + wm + i * 16 + quad * 4;
                f32x4_t ov;
#pragma unroll
                for (int r = 0; r < 4; r++) ov[r] = acc[i][j][r] + bias;
                *(f32x4_t*)(Yf + base + m0) = ov;
            }
        } else {
            u16* Yh = (u16*)Y;
#pragma unroll
            for (int i = 0; i < 4; i++) {
                int m0 = hw0 + wm + i * 16 + quad * 4;
                u32 lo = (u32)f2bf(acc[i][j][0] + bias) | ((u32)f2bf(acc[i][j][1] + bias) << 16);
                u32 hi = (u32)f2bf(acc[i][j][2] + bias) | ((u32)f2bf(acc[i][j][3] + bias) << 16);
                u32* d32 = (u32*)(Yh + base + m0);
                d32[0] = lo; d32[1] = hi;
            }
        }
    }
}

// ---------------------------------------------------------------------------
extern "C" void kernel_launch(void* const* d_in, const int* in_sizes, int n_in,
                              void* d_out, int out_size, void* d_ws, size_t ws_size,
                              hipStream_t stream) {
    (void)in_sizes; (void)n_in; (void)out_size; (void)ws_size;
    const void* x  = d_in[0];
    const void* W1 = d_in[1];
    const void* b1 = d_in[2];
    const void* W2 = d_in[3];
    const void* b2 = d_in[4];
    const u16* xu = (const u16*)x;

    char* ws = (char*)d_ws;
    const size_t MB32 = (size_t)32 * 1024 * 1024;
    u16* xT  = (u16*)(ws);              // 32 MiB; reused as attention output Op
    u16* Q2  = (u16*)(ws + MB32);       // 32 MiB  [b][head][hw][e]
    u16* K2  = (u16*)(ws + 2 * MB32);   // 32 MiB
    u16* V2  = (u16*)(ws + 3 * MB32);   // 32 MiB
    u16* W1b = (u16*)(ws + 4 * MB32);   // 196608 elems (grouped-QKV rows)
    u16* b1b = W1b + 196608;            // 768
    u16* W2b = b1b + 768;               // 65536
    u16* b2b = W2b + 65536;             // 256
    u16* Op  = xT;                      // overlay: xT dead after gemm_qkv

    conv_w  <<<1028, 256, 0, stream>>>(xu, W1, b1, W2, b2, W1b, b1b, W2b, b2b);
    conv_x  <<<dim3(64, 4, 16), 256, 0, stream>>>(x, xT);
    gemm_qkv<<<4096, 256, 0, stream>>>(xT, W1b, b1b, Q2, K2, V2);
    attn_kernel<<<dim3(64, 8, 16), 256, 0, stream>>>(Q2, K2, V2, Op);
    gemm_out<<<dim3(512, 2), 256, 0, stream>>>(xu, Op, W2b, b2b, d_out);
}